// Round 13
// baseline (40.224 us; speedup 1.0000x reference)
//
#include <hip/hip_runtime.h>
#include <math.h>

#define GSZ   16
#define NPIX  256
#define LBIG  1.0e6f
#define PW    18
#define PP18  324
#define HBS   (PP18 * 16)       // bytes per oc-block in h tile

typedef __fp16 f16x8 __attribute__((ext_vector_type(8)));
typedef float  f32x4 __attribute__((ext_vector_type(4)));
typedef __fp16 h2v   __attribute__((ext_vector_type(2)));
union UH2 { unsigned u; h2v h; };
union F8U { f16x8 h; uint4 u; unsigned w[4]; };
union UF  { unsigned u; float f; };

__device__ __forceinline__ unsigned pk2(float a, float b) {
    UH2 u; u.h = __builtin_amdgcn_cvt_pkrtz(a, b);
    return u.u;
}
// value from lane-1 within each 16-lane row: DPP row_shr:1
__device__ __forceinline__ float dpp_up1(float x) {
    UF s; s.f = x;
    UF r; r.u = __builtin_amdgcn_update_dpp(0, (int)s.u, 0x111, 0xF, 0xF, true);
    return r.f;
}
// value from lane+1 within each 16-lane row: DPP row_shl:1
__device__ __forceinline__ float dpp_dn1(float x) {
    UF s; s.f = x;
    UF r; r.u = __builtin_amdgcn_update_dpp(0, (int)s.u, 0x101, 0xF, 0xF, true);
    return r.f;
}

// ---- prep: pack weights into MFMA fragment order ----
__global__ void pack_weights(const float* __restrict__ w1,
                             const float* __restrict__ w2,
                             __fp16* __restrict__ pw) {
    int i = blockIdx.x * 256 + threadIdx.x;
    if (i < 4096) {
        int j = i & 7, lane = (i >> 3) & 63, t = i >> 9;   // t = ks*4+nt
        int ks = t >> 2, nt = t & 3;
        int oc = nt * 16 + (lane & 15);
        int k  = ks * 32 + ((lane >> 4) & 3) * 8 + j;
        int tap = k >> 2, cls = k & 3;
        pw[i] = (tap < 9) ? (__fp16)w1[oc * 36 + cls * 9 + tap] : (__fp16)0.0f;
    } else if (i < 4096 + 9216) {
        int m = i - 4096;
        int j = m & 7, lane = (m >> 3) & 63, t = m >> 9;   // t = tap*2+ks
        int ks = t & 1, tap = t >> 1;
        int u  = lane & 15;
        int oc = ks * 32 + ((lane >> 4) & 3) * 8 + j;
        pw[i] = (u < 4) ? (__fp16)w2[u * 576 + oc * 9 + tap] : (__fp16)0.0f;
    }
}

// ring index for border pixel t in [0,68) of the 18x18 ring
__device__ __forceinline__ int ring_idx(int t) {
    return (t < 18) ? t
         : (t < 36) ? (306 + (t - 18))
         : (t < 52) ? ((t - 35) * PW)
                    : ((t - 51) * PW + 17);
}

__global__ __launch_bounds__(256, 2) void semirl_kernel(
    const float*  __restrict__ grid_cnt,  // (B,4,16,16)
    const int*    __restrict__ loc,       // (B,2)
    const int*    __restrict__ goal,      // (B,2)
    const float*  __restrict__ theta,     // (4,16,16)
    const float*  __restrict__ b1,        // (64)
    const float*  __restrict__ b2,        // (4)
    const __fp16* __restrict__ pw,        // packed weight fragments (d_ws)
    float*        __restrict__ out,       // logits (B,4) then probs (B,4)
    int B)
{
    const int b0   = blockIdx.x * 2;      // 2 batch elements per block
    const int tid  = threadIdx.x;
    const int lane = tid & 63;
    const int wv   = tid >> 6;            // wave id 0..3; waves 0,1 own VI elems
    const int g    = (lane >> 4) & 3;     // k-group / row-group
    const int ln   = lane & 15;

    __shared__ uint2 s_sem[PP18];             // fp16x2 class pairs, zero ring (2.6K)
    __shared__ uint4 s_h4[8 * PP18];          // h: [ocblk][ringpix] 16B (41.5K)
    __shared__ uint2 s_costh[2][NPIX];        // cost fp16 pairs [elem][pix] (4K)
    char*  s_hb   = (char*)s_h4;
    float* s_gout = (float*)s_h4;             // [2][NPIX] aliased (h dead post-conv)

    // ---- prefetch all globals (latency hides under phase 0) ----
    F8U w1f[2][4];
    {
        const uint4* p1 = (const uint4*)pw;
        #pragma unroll
        for (int ks = 0; ks < 2; ++ks)
            #pragma unroll
            for (int nt = 0; nt < 4; ++nt)
                w1f[ks][nt].u = p1[(ks * 4 + nt) * 64 + lane];
    }
    F8U w2f[9][2];
    {
        const uint4* p2 = (const uint4*)(pw + 4096);
        #pragma unroll
        for (int tp = 0; tp < 9; ++tp)
            #pragma unroll
            for (int ks = 0; ks < 2; ++ks)
                w2f[tp][ks].u = p2[(tp * 2 + ks) * 64 + lane];
    }
    float4 bias1v[4];
    #pragma unroll
    for (int nt = 0; nt < 4; ++nt)
        bias1v[nt] = *(const float4*)&b1[nt * 16 + g * 4];
    const float4 b2v = *(const float4*)b2;

    const int eidx = b0 + (wv & 1);        // waves 0,1 own VI elements
    const int grr = goal[2 * eidx], gcc = goal[2 * eidx + 1];
    const int lr  = loc[2 * eidx],  lc  = loc[2 * eidx + 1];

    float th[4], gi[2][4];
    #pragma unroll
    for (int c = 0; c < 4; ++c) th[c] = theta[c * NPIX + tid];
    #pragma unroll
    for (int e = 0; e < 2; ++e)
        #pragma unroll
        for (int c = 0; c < 4; ++c)
            gi[e][c] = grid_cnt[(size_t)(b0 + e) * (4 * NPIX) + c * NPIX + tid];

    // ---- phase 0: ring zeros (once) + softmax elem 0 ----
    if (tid < 68) s_sem[ring_idx(tid)] = make_uint2(0u, 0u);
    for (int i2 = tid; i2 < 544; i2 += 256) {
        int qq = ring_idx(i2 >> 3);
        s_h4[(i2 & 7) * PP18 + qq] = make_uint4(0u, 0u, 0u, 0u);
    }
    const int pr = tid >> 4, pc = tid & 15;
    {
        float x0 = gi[0][0] * th[0], x1 = gi[0][1] * th[1];
        float x2 = gi[0][2] * th[2], x3 = gi[0][3] * th[3];
        float m  = fmaxf(fmaxf(x0, x1), fmaxf(x2, x3));
        float e0 = __expf(x0 - m), e1 = __expf(x1 - m);
        float e2 = __expf(x2 - m), e3 = __expf(x3 - m);
        float inv = 1.0f / (e0 + e1 + e2 + e3);
        s_sem[(pr + 1) * PW + (pc + 1)] =
            make_uint2(pk2(e0 * inv, e1 * inv), pk2(e2 * inv, e3 * inv));
    }
    __syncthreads();

    const int off0 = (g == 0) ? (-PW - 1) : (g == 1) ? (-PW + 1) : (g == 2) ? 0 : (PW - 1);
    const int off1 = (g == 0) ? (-PW)     : (g == 1) ? (-1)      : (g == 2) ? 1 : PW;
    const int OFF[9] = { -PW - 1, -PW, -PW + 1, -1, 0, 1, PW - 1, PW, PW + 1 };

    // ---- element-sequential convs: all 4 waves cooperate per element ----
    #pragma unroll
    for (int e = 0; e < 2; ++e) {
        // conv1 (swapped: D' = W^T x Act^T), write h fragments
        #pragma unroll
        for (int i = 0; i < 4; ++i) {
            const int mt = wv * 4 + i;
            const int pp = (mt + 1) * PW + (ln + 1);
            const uint2 A0 = s_sem[pp + off0];
            const uint2 A1 = s_sem[pp + off1];
            const uint2 A2 = s_sem[pp + (PW + 1)];   // tap8; dead slots zero-weighted
            F8U a0, a1;
            a0.w[0] = A0.x; a0.w[1] = A0.y; a0.w[2] = A1.x; a0.w[3] = A1.y;
            a1.w[0] = A2.x; a1.w[1] = A2.y; a1.w[2] = 0u;  a1.w[3] = 0u;
            char* wbase = s_hb + (g >> 1) * HBS + pp * 16 + (g & 1) * 8;
            #pragma unroll
            for (int nt = 0; nt < 4; ++nt) {
                f32x4 acc = { bias1v[nt].x, bias1v[nt].y, bias1v[nt].z, bias1v[nt].w };
                acc = __builtin_amdgcn_mfma_f32_16x16x32_f16(w1f[0][nt].h, a0.h, acc, 0, 0, 0);
                acc = __builtin_amdgcn_mfma_f32_16x16x32_f16(w1f[1][nt].h, a1.h, acc, 0, 0, 0);
                uint2 hv;
                hv.x = pk2(fmaxf(acc[0], 0.0f), fmaxf(acc[1], 0.0f));
                hv.y = pk2(fmaxf(acc[2], 0.0f), fmaxf(acc[3], 0.0f));
                *(uint2*)(wbase + nt * (2 * HBS)) = hv;
            }
        }
        __syncthreads();           // h ready; sem free

        // conv2 (swapped): 9 tap-GEMMs; offsets fold into ds_read immediates
        #pragma unroll
        for (int i = 0; i < 4; ++i) {
            const int mt = wv * 4 + i;
            const int pp = (mt + 1) * PW + (ln + 1);
            const char* hb0 = s_hb + g * HBS + pp * 16;        // ks=0 block
            const char* hb1 = hb0 + 4 * HBS;                   // ks=1 block
            f32x4 cacc;
            cacc[0] = (g == 0) ? b2v.x : 0.0f;
            cacc[1] = (g == 0) ? b2v.y : 0.0f;
            cacc[2] = (g == 0) ? b2v.z : 0.0f;
            cacc[3] = (g == 0) ? b2v.w : 0.0f;
            #pragma unroll
            for (int tp = 0; tp < 9; ++tp) {
                F8U af;
                af.u = *(const uint4*)(hb0 + OFF[tp] * 16);
                cacc = __builtin_amdgcn_mfma_f32_16x16x32_f16(w2f[tp][0].h, af.h, cacc, 0, 0, 0);
                af.u = *(const uint4*)(hb1 + OFF[tp] * 16);
                cacc = __builtin_amdgcn_mfma_f32_16x16x32_f16(w2f[tp][1].h, af.h, cacc, 0, 0, 0);
            }
            if (g == 0) {
                float c0, c1, c2, c3;
                c0 = fmaxf(cacc[0], 0.0f) + __logf(1.0f + __expf(-fabsf(cacc[0]))) + 1e-6f;
                c1 = fmaxf(cacc[1], 0.0f) + __logf(1.0f + __expf(-fabsf(cacc[1]))) + 1e-6f;
                c2 = fmaxf(cacc[2], 0.0f) + __logf(1.0f + __expf(-fabsf(cacc[2]))) + 1e-6f;
                c3 = fmaxf(cacc[3], 0.0f) + __logf(1.0f + __expf(-fabsf(cacc[3]))) + 1e-6f;
                s_costh[e][mt * 16 + ln] = make_uint2(pk2(c0, c1), pk2(c2, c3));
            }
        }
        // softmax for next element (sem readers done at conv1's barrier)
        if (e < 1) {
            float x0 = gi[1][0] * th[0], x1 = gi[1][1] * th[1];
            float x2 = gi[1][2] * th[2], x3 = gi[1][3] * th[3];
            float m  = fmaxf(fmaxf(x0, x1), fmaxf(x2, x3));
            float e0 = __expf(x0 - m), e1 = __expf(x1 - m);
            float e2 = __expf(x2 - m), e3 = __expf(x3 - m);
            float inv = 1.0f / (e0 + e1 + e2 + e3);
            s_sem[(pr + 1) * PW + (pc + 1)] =
                make_uint2(pk2(e0 * inv, e1 * inv), pk2(e2 * inv, e3 * inv));
        }
        __syncthreads();           // h free for next conv1; cost[e] committed
    }

    // ---- value iteration: waves 0,1 own elements b0+0, b0+1 ----
    if (wv < 2) {
        const int cv  = ln;
        const int rgv = g;
        const int r0  = rgv * 4;

        float cs[4][4];
        #pragma unroll
        for (int i = 0; i < 4; ++i) {
            const uint2 cw = s_costh[wv][(r0 + i) * GSZ + cv];
            UH2 a, bq; a.u = cw.x; bq.u = cw.y;
            cs[i][0] = (float)a.h[0];  cs[i][1] = (float)a.h[1];
            cs[i][2] = (float)bq.h[0]; cs[i][3] = (float)bq.h[1];
        }

        float gg[4];
        #pragma unroll
        for (int i = 0; i < 4; ++i)
            gg[i] = (cv == gcc && (r0 + i) == grr) ? 0.0f : LBIG;

        for (int k = 0; k < 128; ++k) {
            const float gu = __shfl_up(gg[3], 16);
            const float gd = __shfl_down(gg[0], 16);
            const float up0 = (rgv > 0) ? gu : LBIG;
            const float dn3 = (rgv < 3) ? gd : LBIG;
            bool ch = false;
            #pragma unroll
            for (int s = 0; s < 2; ++s) {
                float lf[4], rt[4];
                #pragma unroll
                for (int i = 0; i < 4; ++i) { lf[i] = dpp_up1(gg[i]); rt[i] = dpp_dn1(gg[i]); }
                #pragma unroll
                for (int i = 0; i < 4; ++i) {
                    lf[i] = (cv > 0)  ? lf[i] : LBIG;
                    rt[i] = (cv < 15) ? rt[i] : LBIG;
                }
                const float up[4] = { up0, gg[0], gg[1], gg[2] };
                const float dn[4] = { gg[1], gg[2], gg[3], dn3 };
                #pragma unroll
                for (int i = 0; i < 4; ++i) {
                    float q = fminf(fminf(cs[i][0] + up[i], cs[i][1] + dn[i]),
                                    fminf(cs[i][2] + lf[i], cs[i][3] + rt[i]));
                    float ng = fminf(gg[i], q);
                    ch = ch || (ng < gg[i]);
                    gg[i] = ng;
                }
            }
            if (__ballot(ch) == 0ULL) break;   // per-wave fixed point
        }

        #pragma unroll
        for (int i = 0; i < 4; ++i)
            s_gout[wv * NPIX + (r0 + i) * GSZ + cv] = gg[i];

        // ---- Q gather + output softmax: lane 0 of waves 0,1 ----
        if (lane == 0) {
            const int lp = lr * GSZ + lc;
            const uint2 cw = s_costh[wv][lp];
            UH2 a, bq; a.u = cw.x; bq.u = cw.y;
            float Q0 = (float)a.h[0]  + s_gout[wv * NPIX + lp - GSZ];
            float Q1 = (float)a.h[1]  + s_gout[wv * NPIX + lp + GSZ];
            float Q2 = (float)bq.h[0] + s_gout[wv * NPIX + lp - 1];
            float Q3 = (float)bq.h[1] + s_gout[wv * NPIX + lp + 1];
            float l0 = -Q0, l1 = -Q1, l2 = -Q2, l3 = -Q3;
            float m  = fmaxf(fmaxf(l0, l1), fmaxf(l2, l3));
            float e0 = __expf(l0 - m), e1 = __expf(l1 - m);
            float e2 = __expf(l2 - m), e3 = __expf(l3 - m);
            float inv = 1.0f / (e0 + e1 + e2 + e3);
            float* lo = out + (size_t)eidx * 4;
            float* po = out + (size_t)B * 4 + (size_t)eidx * 4;
            lo[0] = l0; lo[1] = l1; lo[2] = l2; lo[3] = l3;
            po[0] = e0 * inv; po[1] = e1 * inv; po[2] = e2 * inv; po[3] = e3 * inv;
        }
    }
}

extern "C" void kernel_launch(void* const* d_in, const int* in_sizes, int n_in,
                              void* d_out, int out_size, void* d_ws, size_t ws_size,
                              hipStream_t stream) {
    const float* grid_cnt = (const float*)d_in[0];
    const int*   loc      = (const int*)  d_in[1];
    const int*   goal     = (const int*)  d_in[2];
    const float* theta    = (const float*)d_in[3];
    const float* w1       = (const float*)d_in[4];
    const float* b1       = (const float*)d_in[5];
    const float* w2       = (const float*)d_in[6];
    const float* b2       = (const float*)d_in[7];
    float*       outp     = (float*)d_out;
    __fp16*      pw       = (__fp16*)d_ws;     // needs 26624 B
    const int B = in_sizes[1] / 2;   // loc_batch is (B,2)

    hipLaunchKernelGGL(pack_weights, dim3(52), dim3(256), 0, stream, w1, w2, pw);
    hipLaunchKernelGGL(semirl_kernel, dim3(B / 2), dim3(256), 0, stream,
                       grid_cnt, loc, goal, theta, b1, b2, pw, outp, B);
}

// Round 14
// 35.821 us; speedup vs baseline: 1.1229x; 1.1229x over previous
//
#include <hip/hip_runtime.h>
#include <math.h>

#define GSZ   16
#define NPIX  256
#define LBIG  1.0e6f
#define PW    18
#define PP18  324
#define HBS   (PP18 * 16)       // bytes per oc-block in h tile

typedef __fp16 f16x8 __attribute__((ext_vector_type(8)));
typedef float  f32x4 __attribute__((ext_vector_type(4)));
typedef __fp16 h2v   __attribute__((ext_vector_type(2)));
union UH2 { unsigned u; h2v h; };
union F8U { f16x8 h; uint4 u; unsigned w[4]; };
union UF  { unsigned u; float f; };

__device__ __forceinline__ unsigned pk2(float a, float b) {
    UH2 u; u.h = __builtin_amdgcn_cvt_pkrtz(a, b);
    return u.u;
}
// value from lane-1 within each 16-lane row: DPP row_shr:1 (0 at lane 0)
__device__ __forceinline__ unsigned dpp_shr1_u(unsigned x) {
    return (unsigned)__builtin_amdgcn_update_dpp(0, (int)x, 0x111, 0xF, 0xF, true);
}
// value from lane+1 within each 16-lane row: DPP row_shl:1 (0 at lane 15)
__device__ __forceinline__ unsigned dpp_shl1_u(unsigned x) {
    return (unsigned)__builtin_amdgcn_update_dpp(0, (int)x, 0x101, 0xF, 0xF, true);
}
__device__ __forceinline__ float dpp_up1(float x) {
    UF s; s.f = x; UF r;
    r.u = (unsigned)__builtin_amdgcn_update_dpp(0, (int)s.u, 0x111, 0xF, 0xF, true);
    return r.f;
}
__device__ __forceinline__ float dpp_dn1(float x) {
    UF s; s.f = x; UF r;
    r.u = (unsigned)__builtin_amdgcn_update_dpp(0, (int)s.u, 0x101, 0xF, 0xF, true);
    return r.f;
}

// ---- prep: pack weights into MFMA fragment order ----
__global__ void pack_weights(const float* __restrict__ w1,
                             const float* __restrict__ w2,
                             __fp16* __restrict__ pw) {
    int i = blockIdx.x * 256 + threadIdx.x;
    if (i < 4096) {
        int j = i & 7, lane = (i >> 3) & 63, t = i >> 9;   // t = ks*4+nt
        int ks = t >> 2, nt = t & 3;
        int oc = nt * 16 + (lane & 15);
        int k  = ks * 32 + ((lane >> 4) & 3) * 8 + j;
        int tap = k >> 2, cls = k & 3;
        pw[i] = (tap < 9) ? (__fp16)w1[oc * 36 + cls * 9 + tap] : (__fp16)0.0f;
    } else if (i < 4096 + 9216) {
        int m = i - 4096;
        int j = m & 7, lane = (m >> 3) & 63, t = m >> 9;   // t = tap*2+ks
        int ks = t & 1, tap = t >> 1;
        int u  = lane & 15;
        int oc = ks * 32 + ((lane >> 4) & 3) * 8 + j;
        pw[i] = (u < 4) ? (__fp16)w2[u * 576 + oc * 9 + tap] : (__fp16)0.0f;
    }
}

// ring index for border pixel t in [0,68) of the 18x18 ring
__device__ __forceinline__ int ring_idx(int t) {
    return (t < 18) ? t
         : (t < 36) ? (306 + (t - 18))
         : (t < 52) ? ((t - 35) * PW)
                    : ((t - 51) * PW + 17);
}

__global__ __launch_bounds__(256, 2) void semirl_kernel(
    const float*  __restrict__ grid_cnt,  // (B,4,16,16)
    const int*    __restrict__ loc,       // (B,2)
    const int*    __restrict__ goal,      // (B,2)
    const float*  __restrict__ theta,     // (4,16,16)
    const float*  __restrict__ b1,        // (64)
    const float*  __restrict__ b2,        // (4)
    const __fp16* __restrict__ pw,        // packed weight fragments (d_ws)
    float*        __restrict__ out,       // logits (B,4) then probs (B,4)
    int B)
{
    const int b0   = blockIdx.x * 4;      // 4 batch elements per block
    const int tid  = threadIdx.x;
    const int lane = tid & 63;
    const int wv   = tid >> 6;            // wave id 0..3 = element owner for VI
    const int g    = (lane >> 4) & 3;     // k-group / row-group
    const int ln   = lane & 15;

    __shared__ uint2 s_sem[PP18];             // fp16x2 class pairs, zero ring (2.6K)
    __shared__ uint4 s_h4[8 * PP18];          // h: [ocblk][ringpix] 16B (41.5K)
    __shared__ uint2 s_costh[4][NPIX];        // cost fp16 pairs [elem][pix] (8K)
    char*  s_hb   = (char*)s_h4;
    float* s_gout = (float*)s_h4;             // [4][NPIX] aliased (h dead post-conv)

    // ---- prefetch all globals (latency hides under phase 0) ----
    F8U w1f[2][4];
    {
        const uint4* p1 = (const uint4*)pw;
        #pragma unroll
        for (int ks = 0; ks < 2; ++ks)
            #pragma unroll
            for (int nt = 0; nt < 4; ++nt)
                w1f[ks][nt].u = p1[(ks * 4 + nt) * 64 + lane];
    }
    F8U w2f[9][2];
    {
        const uint4* p2 = (const uint4*)(pw + 4096);
        #pragma unroll
        for (int tp = 0; tp < 9; ++tp)
            #pragma unroll
            for (int ks = 0; ks < 2; ++ks)
                w2f[tp][ks].u = p2[(tp * 2 + ks) * 64 + lane];
    }
    float4 bias1v[4];
    #pragma unroll
    for (int nt = 0; nt < 4; ++nt)
        bias1v[nt] = *(const float4*)&b1[nt * 16 + g * 4];
    const float4 b2v = *(const float4*)b2;

    const int eidx = b0 + wv;              // this wave's VI element
    const int grr = goal[2 * eidx], gcc = goal[2 * eidx + 1];
    const int lr  = loc[2 * eidx],  lc  = loc[2 * eidx + 1];

    float th[4], gi[4][4];
    #pragma unroll
    for (int c = 0; c < 4; ++c) th[c] = theta[c * NPIX + tid];
    #pragma unroll
    for (int e = 0; e < 4; ++e)
        #pragma unroll
        for (int c = 0; c < 4; ++c)
            gi[e][c] = grid_cnt[(size_t)(b0 + e) * (4 * NPIX) + c * NPIX + tid];

    // ---- phase 0: ring zeros (once) + softmax elem 0 ----
    if (tid < 68) s_sem[ring_idx(tid)] = make_uint2(0u, 0u);
    for (int i2 = tid; i2 < 544; i2 += 256) {
        int qq = ring_idx(i2 >> 3);
        s_h4[(i2 & 7) * PP18 + qq] = make_uint4(0u, 0u, 0u, 0u);
    }
    const int pr = tid >> 4, pc = tid & 15;
    {
        float x0 = gi[0][0] * th[0], x1 = gi[0][1] * th[1];
        float x2 = gi[0][2] * th[2], x3 = gi[0][3] * th[3];
        float m  = fmaxf(fmaxf(x0, x1), fmaxf(x2, x3));
        float e0 = __expf(x0 - m), e1 = __expf(x1 - m);
        float e2 = __expf(x2 - m), e3 = __expf(x3 - m);
        float inv = 1.0f / (e0 + e1 + e2 + e3);
        s_sem[(pr + 1) * PW + (pc + 1)] =
            make_uint2(pk2(e0 * inv, e1 * inv), pk2(e2 * inv, e3 * inv));
    }
    __syncthreads();

    const int off0 = (g == 0) ? (-PW - 1) : (g == 1) ? (-PW + 1) : (g == 2) ? 0 : (PW - 1);
    const int off1 = (g == 0) ? (-PW)     : (g == 1) ? (-1)      : (g == 2) ? 1 : PW;

    // ---- element-sequential convs: all 4 waves cooperate per element ----
    #pragma unroll
    for (int e = 0; e < 4; ++e) {
        // conv1 (swapped: D' = W^T x Act^T), write h fragments
        #pragma unroll
        for (int i = 0; i < 4; ++i) {
            const int mt = wv * 4 + i;
            const int pp = (mt + 1) * PW + (ln + 1);
            const uint2 A0 = s_sem[pp + off0];
            const uint2 A1 = s_sem[pp + off1];
            const uint2 A2 = s_sem[pp + (PW + 1)];   // tap8; dead slots zero-weighted
            F8U a0, a1;
            a0.w[0] = A0.x; a0.w[1] = A0.y; a0.w[2] = A1.x; a0.w[3] = A1.y;
            a1.w[0] = A2.x; a1.w[1] = A2.y; a1.w[2] = 0u;  a1.w[3] = 0u;
            char* wbase = s_hb + (g >> 1) * HBS + pp * 16 + (g & 1) * 8;
            #pragma unroll
            for (int nt = 0; nt < 4; ++nt) {
                f32x4 acc = { bias1v[nt].x, bias1v[nt].y, bias1v[nt].z, bias1v[nt].w };
                acc = __builtin_amdgcn_mfma_f32_16x16x32_f16(w1f[0][nt].h, a0.h, acc, 0, 0, 0);
                acc = __builtin_amdgcn_mfma_f32_16x16x32_f16(w1f[1][nt].h, a1.h, acc, 0, 0, 0);
                uint2 hv;
                hv.x = pk2(fmaxf(acc[0], 0.0f), fmaxf(acc[1], 0.0f));
                hv.y = pk2(fmaxf(acc[2], 0.0f), fmaxf(acc[3], 0.0f));
                *(uint2*)(wbase + nt * (2 * HBS)) = hv;
            }
        }
        __syncthreads();           // h ready; sem free

        // conv2 (swapped): per row, read center-column fragments once;
        // derive dc=+-1 fragments via DPP row_shr/shl (bound_ctrl zeros = column pad).
        // MFMA order per row: dc=-1,0,+1 x ks=0,1  == tap-major order (bit-identical).
        #pragma unroll
        for (int i = 0; i < 4; ++i) {
            const int mt = wv * 4 + i;
            const int pp = (mt + 1) * PW + (ln + 1);
            const char* hb0 = s_hb + g * HBS + pp * 16;        // ks=0 block
            const char* hb1 = hb0 + 4 * HBS;                   // ks=1 block
            f32x4 cacc;
            cacc[0] = (g == 0) ? b2v.x : 0.0f;
            cacc[1] = (g == 0) ? b2v.y : 0.0f;
            cacc[2] = (g == 0) ? b2v.z : 0.0f;
            cacc[3] = (g == 0) ? b2v.w : 0.0f;
            #pragma unroll
            for (int dr = 0; dr < 3; ++dr) {
                const int ro = (dr - 1) * PW * 16;
                F8U c0, c1, l0, l1, r0, r1;
                c0.u = *(const uint4*)(hb0 + ro);
                c1.u = *(const uint4*)(hb1 + ro);
                #pragma unroll
                for (int d = 0; d < 4; ++d) {
                    l0.w[d] = dpp_shr1_u(c0.w[d]);  r0.w[d] = dpp_shl1_u(c0.w[d]);
                    l1.w[d] = dpp_shr1_u(c1.w[d]);  r1.w[d] = dpp_shl1_u(c1.w[d]);
                }
                const int tpl = dr * 3, tpc = dr * 3 + 1, tpr = dr * 3 + 2;
                cacc = __builtin_amdgcn_mfma_f32_16x16x32_f16(w2f[tpl][0].h, l0.h, cacc, 0, 0, 0);
                cacc = __builtin_amdgcn_mfma_f32_16x16x32_f16(w2f[tpl][1].h, l1.h, cacc, 0, 0, 0);
                cacc = __builtin_amdgcn_mfma_f32_16x16x32_f16(w2f[tpc][0].h, c0.h, cacc, 0, 0, 0);
                cacc = __builtin_amdgcn_mfma_f32_16x16x32_f16(w2f[tpc][1].h, c1.h, cacc, 0, 0, 0);
                cacc = __builtin_amdgcn_mfma_f32_16x16x32_f16(w2f[tpr][0].h, r0.h, cacc, 0, 0, 0);
                cacc = __builtin_amdgcn_mfma_f32_16x16x32_f16(w2f[tpr][1].h, r1.h, cacc, 0, 0, 0);
            }
            if (g == 0) {
                float c0s, c1s, c2s, c3s;
                c0s = fmaxf(cacc[0], 0.0f) + __logf(1.0f + __expf(-fabsf(cacc[0]))) + 1e-6f;
                c1s = fmaxf(cacc[1], 0.0f) + __logf(1.0f + __expf(-fabsf(cacc[1]))) + 1e-6f;
                c2s = fmaxf(cacc[2], 0.0f) + __logf(1.0f + __expf(-fabsf(cacc[2]))) + 1e-6f;
                c3s = fmaxf(cacc[3], 0.0f) + __logf(1.0f + __expf(-fabsf(cacc[3]))) + 1e-6f;
                s_costh[e][mt * 16 + ln] = make_uint2(pk2(c0s, c1s), pk2(c2s, c3s));
            }
        }
        // softmax for next element (sem readers done at conv1's barrier)
        if (e < 3) {
            float x0 = gi[e+1][0] * th[0], x1 = gi[e+1][1] * th[1];
            float x2 = gi[e+1][2] * th[2], x3 = gi[e+1][3] * th[3];
            float m  = fmaxf(fmaxf(x0, x1), fmaxf(x2, x3));
            float e0 = __expf(x0 - m), e1 = __expf(x1 - m);
            float e2 = __expf(x2 - m), e3 = __expf(x3 - m);
            float inv = 1.0f / (e0 + e1 + e2 + e3);
            s_sem[(pr + 1) * PW + (pc + 1)] =
                make_uint2(pk2(e0 * inv, e1 * inv), pk2(e2 * inv, e3 * inv));
        }
        __syncthreads();           // h free for next conv1; cost[e] committed
    }

    // ---- value iteration: wave wv owns element b0+wv (Jacobi, 2 inner/outer) ----
    {
        const int cv  = ln;
        const int rgv = g;
        const int r0  = rgv * 4;

        float cs[4][4];
        #pragma unroll
        for (int i = 0; i < 4; ++i) {
            const uint2 cw = s_costh[wv][(r0 + i) * GSZ + cv];
            UH2 a, bq; a.u = cw.x; bq.u = cw.y;
            cs[i][0] = (float)a.h[0];  cs[i][1] = (float)a.h[1];
            cs[i][2] = (float)bq.h[0]; cs[i][3] = (float)bq.h[1];
        }

        float gg[4];
        #pragma unroll
        for (int i = 0; i < 4; ++i)
            gg[i] = (cv == gcc && (r0 + i) == grr) ? 0.0f : LBIG;

        for (int k = 0; k < 128; ++k) {
            const float gu = __shfl_up(gg[3], 16);
            const float gd = __shfl_down(gg[0], 16);
            const float up0 = (rgv > 0) ? gu : LBIG;
            const float dn3 = (rgv < 3) ? gd : LBIG;
            bool ch = false;
            #pragma unroll
            for (int s = 0; s < 2; ++s) {
                float lf[4], rt[4];
                #pragma unroll
                for (int i = 0; i < 4; ++i) { lf[i] = dpp_up1(gg[i]); rt[i] = dpp_dn1(gg[i]); }
                #pragma unroll
                for (int i = 0; i < 4; ++i) {
                    lf[i] = (cv > 0)  ? lf[i] : LBIG;
                    rt[i] = (cv < 15) ? rt[i] : LBIG;
                }
                const float up[4] = { up0, gg[0], gg[1], gg[2] };
                const float dn[4] = { gg[1], gg[2], gg[3], dn3 };
                #pragma unroll
                for (int i = 0; i < 4; ++i) {
                    float q = fminf(fminf(cs[i][0] + up[i], cs[i][1] + dn[i]),
                                    fminf(cs[i][2] + lf[i], cs[i][3] + rt[i]));
                    float ng = fminf(gg[i], q);
                    ch = ch || (ng < gg[i]);
                    gg[i] = ng;
                }
            }
            if (__ballot(ch) == 0ULL) break;   // per-wave fixed point
        }

        #pragma unroll
        for (int i = 0; i < 4; ++i)
            s_gout[wv * NPIX + (r0 + i) * GSZ + cv] = gg[i];
    }
    // intra-wave LDS ordering only (same wave writes then reads; no barrier)

    // ---- Q gather + output softmax: lane 0 of each wave ----
    if (lane == 0) {
        const int lp = lr * GSZ + lc;
        const uint2 cw = s_costh[wv][lp];
        UH2 a, bq; a.u = cw.x; bq.u = cw.y;
        float Q0 = (float)a.h[0]  + s_gout[wv * NPIX + lp - GSZ];
        float Q1 = (float)a.h[1]  + s_gout[wv * NPIX + lp + GSZ];
        float Q2 = (float)bq.h[0] + s_gout[wv * NPIX + lp - 1];
        float Q3 = (float)bq.h[1] + s_gout[wv * NPIX + lp + 1];
        float l0 = -Q0, l1 = -Q1, l2 = -Q2, l3 = -Q3;
        float m  = fmaxf(fmaxf(l0, l1), fmaxf(l2, l3));
        float e0 = __expf(l0 - m), e1 = __expf(l1 - m);
        float e2 = __expf(l2 - m), e3 = __expf(l3 - m);
        float inv = 1.0f / (e0 + e1 + e2 + e3);
        float* lo = out + (size_t)eidx * 4;
        float* po = out + (size_t)B * 4 + (size_t)eidx * 4;
        lo[0] = l0; lo[1] = l1; lo[2] = l2; lo[3] = l3;
        po[0] = e0 * inv; po[1] = e1 * inv; po[2] = e2 * inv; po[3] = e3 * inv;
    }
}

extern "C" void kernel_launch(void* const* d_in, const int* in_sizes, int n_in,
                              void* d_out, int out_size, void* d_ws, size_t ws_size,
                              hipStream_t stream) {
    const float* grid_cnt = (const float*)d_in[0];
    const int*   loc      = (const int*)  d_in[1];
    const int*   goal     = (const int*)  d_in[2];
    const float* theta    = (const float*)d_in[3];
    const float* w1       = (const float*)d_in[4];
    const float* b1       = (const float*)d_in[5];
    const float* w2       = (const float*)d_in[6];
    const float* b2       = (const float*)d_in[7];
    float*       outp     = (float*)d_out;
    __fp16*      pw       = (__fp16*)d_ws;     // needs 26624 B
    const int B = in_sizes[1] / 2;   // loc_batch is (B,2)

    hipLaunchKernelGGL(pack_weights, dim3(52), dim3(256), 0, stream, w1, w2, pw);
    hipLaunchKernelGGL(semirl_kernel, dim3(B / 4), dim3(256), 0, stream,
                       grid_cnt, loc, goal, theta, b1, b2, pw, outp, B);
}

// Round 15
// 33.983 us; speedup vs baseline: 1.1837x; 1.0541x over previous
//
#include <hip/hip_runtime.h>
#include <math.h>

#define GSZ   16
#define NPIX  256
#define LBIG  1.0e6f
#define PW    18
#define PP18  324
#define HBS   (PP18 * 16)       // bytes per oc-block in h tile

typedef __fp16 f16x8 __attribute__((ext_vector_type(8)));
typedef float  f32x4 __attribute__((ext_vector_type(4)));
typedef __fp16 h2v   __attribute__((ext_vector_type(2)));
union UH2 { unsigned u; h2v h; };
union F8U { f16x8 h; uint4 u; unsigned w[4]; };
union UF  { unsigned u; float f; };

__device__ __forceinline__ unsigned pk2(float a, float b) {
    UH2 u; u.h = __builtin_amdgcn_cvt_pkrtz(a, b);
    return u.u;
}
// value from lane-1 within each 16-lane row: DPP row_shr:1
__device__ __forceinline__ float dpp_up1(float x) {
    UF s; s.f = x; UF r;
    r.u = (unsigned)__builtin_amdgcn_update_dpp(0, (int)s.u, 0x111, 0xF, 0xF, true);
    return r.f;
}
// value from lane+1 within each 16-lane row: DPP row_shl:1
__device__ __forceinline__ float dpp_dn1(float x) {
    UF s; s.f = x; UF r;
    r.u = (unsigned)__builtin_amdgcn_update_dpp(0, (int)s.u, 0x101, 0xF, 0xF, true);
    return r.f;
}

// ---- prep: pack weights into MFMA fragment order ----
__global__ void pack_weights(const float* __restrict__ w1,
                             const float* __restrict__ w2,
                             __fp16* __restrict__ pw) {
    int i = blockIdx.x * 256 + threadIdx.x;
    if (i < 4096) {
        int j = i & 7, lane = (i >> 3) & 63, t = i >> 9;   // t = ks*4+nt
        int ks = t >> 2, nt = t & 3;
        int oc = nt * 16 + (lane & 15);
        int k  = ks * 32 + ((lane >> 4) & 3) * 8 + j;
        int tap = k >> 2, cls = k & 3;
        pw[i] = (tap < 9) ? (__fp16)w1[oc * 36 + cls * 9 + tap] : (__fp16)0.0f;
    } else if (i < 4096 + 9216) {
        int m = i - 4096;
        int j = m & 7, lane = (m >> 3) & 63, t = m >> 9;   // t = tap*2+ks
        int ks = t & 1, tap = t >> 1;
        int u  = lane & 15;
        int oc = ks * 32 + ((lane >> 4) & 3) * 8 + j;
        pw[i] = (u < 4) ? (__fp16)w2[u * 576 + oc * 9 + tap] : (__fp16)0.0f;
    }
}

// ring index for border pixel t in [0,68) of the 18x18 ring
__device__ __forceinline__ int ring_idx(int t) {
    return (t < 18) ? t
         : (t < 36) ? (306 + (t - 18))
         : (t < 52) ? ((t - 35) * PW)
                    : ((t - 51) * PW + 17);
}

__global__ __launch_bounds__(256, 2) void semirl_kernel(
    const float*  __restrict__ grid_cnt,  // (B,4,16,16)
    const int*    __restrict__ loc,       // (B,2)
    const int*    __restrict__ goal,      // (B,2)
    const float*  __restrict__ theta,     // (4,16,16)
    const float*  __restrict__ b1,        // (64)
    const float*  __restrict__ b2,        // (4)
    const __fp16* __restrict__ pw,        // packed weight fragments (d_ws)
    float*        __restrict__ out,       // logits (B,4) then probs (B,4)
    int B)
{
    const int b0   = blockIdx.x * 4;      // 4 batch elements per block
    const int tid  = threadIdx.x;
    const int lane = tid & 63;
    const int wv   = tid >> 6;            // wave id 0..3 = element owner for VI
    const int g    = (lane >> 4) & 3;     // k-group / row-group
    const int ln   = lane & 15;

    __shared__ uint2 s_sem[PP18];             // fp16x2 class pairs, zero ring (2.6K)
    __shared__ uint4 s_h4[8 * PP18];          // h: [ocblk][ringpix] 16B (41.5K)
    __shared__ uint2 s_costh[4][NPIX];        // cost fp16 pairs [elem][pix] (8K)
    char*  s_hb   = (char*)s_h4;
    float* s_gout = (float*)s_h4;             // [4][NPIX] aliased (h dead post-conv)

    // ---- prefetch all globals (latency hides under phase 0) ----
    F8U w1f[2][4];
    {
        const uint4* p1 = (const uint4*)pw;
        #pragma unroll
        for (int ks = 0; ks < 2; ++ks)
            #pragma unroll
            for (int nt = 0; nt < 4; ++nt)
                w1f[ks][nt].u = p1[(ks * 4 + nt) * 64 + lane];
    }
    F8U w2f[9][2];
    {
        const uint4* p2 = (const uint4*)(pw + 4096);
        #pragma unroll
        for (int tp = 0; tp < 9; ++tp)
            #pragma unroll
            for (int ks = 0; ks < 2; ++ks)
                w2f[tp][ks].u = p2[(tp * 2 + ks) * 64 + lane];
    }
    float4 bias1v[4];
    #pragma unroll
    for (int nt = 0; nt < 4; ++nt)
        bias1v[nt] = *(const float4*)&b1[nt * 16 + g * 4];
    const float4 b2v = *(const float4*)b2;

    const int eidx = b0 + wv;              // this wave's VI element
    const int grr = goal[2 * eidx], gcc = goal[2 * eidx + 1];
    const int lr  = loc[2 * eidx],  lc  = loc[2 * eidx + 1];

    float th[4], gi[4][4];
    #pragma unroll
    for (int c = 0; c < 4; ++c) th[c] = theta[c * NPIX + tid];
    #pragma unroll
    for (int e = 0; e < 4; ++e)
        #pragma unroll
        for (int c = 0; c < 4; ++c)
            gi[e][c] = grid_cnt[(size_t)(b0 + e) * (4 * NPIX) + c * NPIX + tid];

    // ---- phase 0: ring zeros (once) + softmax elem 0 ----
    if (tid < 68) s_sem[ring_idx(tid)] = make_uint2(0u, 0u);
    for (int i2 = tid; i2 < 544; i2 += 256) {
        int qq = ring_idx(i2 >> 3);
        s_h4[(i2 & 7) * PP18 + qq] = make_uint4(0u, 0u, 0u, 0u);
    }
    const int pr = tid >> 4, pc = tid & 15;
    {
        float x0 = gi[0][0] * th[0], x1 = gi[0][1] * th[1];
        float x2 = gi[0][2] * th[2], x3 = gi[0][3] * th[3];
        float m  = fmaxf(fmaxf(x0, x1), fmaxf(x2, x3));
        float e0 = __expf(x0 - m), e1 = __expf(x1 - m);
        float e2 = __expf(x2 - m), e3 = __expf(x3 - m);
        float inv = 1.0f / (e0 + e1 + e2 + e3);
        s_sem[(pr + 1) * PW + (pc + 1)] =
            make_uint2(pk2(e0 * inv, e1 * inv), pk2(e2 * inv, e3 * inv));
    }
    __syncthreads();

    const int off0 = (g == 0) ? (-PW - 1) : (g == 1) ? (-PW + 1) : (g == 2) ? 0 : (PW - 1);
    const int off1 = (g == 0) ? (-PW)     : (g == 1) ? (-1)      : (g == 2) ? 1 : PW;
    const int OFF[9] = { -PW - 1, -PW, -PW + 1, -1, 0, 1, PW - 1, PW, PW + 1 };

    // ---- element-sequential convs: all 4 waves cooperate per element ----
    #pragma unroll
    for (int e = 0; e < 4; ++e) {
        // conv1 (swapped: D' = W^T x Act^T), write h fragments
        #pragma unroll
        for (int i = 0; i < 4; ++i) {
            const int mt = wv * 4 + i;
            const int pp = (mt + 1) * PW + (ln + 1);
            const uint2 A0 = s_sem[pp + off0];
            const uint2 A1 = s_sem[pp + off1];
            const uint2 A2 = s_sem[pp + (PW + 1)];   // tap8; dead slots zero-weighted
            F8U a0, a1;
            a0.w[0] = A0.x; a0.w[1] = A0.y; a0.w[2] = A1.x; a0.w[3] = A1.y;
            a1.w[0] = A2.x; a1.w[1] = A2.y; a1.w[2] = 0u;  a1.w[3] = 0u;
            char* wbase = s_hb + (g >> 1) * HBS + pp * 16 + (g & 1) * 8;
            #pragma unroll
            for (int nt = 0; nt < 4; ++nt) {
                f32x4 acc = { bias1v[nt].x, bias1v[nt].y, bias1v[nt].z, bias1v[nt].w };
                acc = __builtin_amdgcn_mfma_f32_16x16x32_f16(w1f[0][nt].h, a0.h, acc, 0, 0, 0);
                acc = __builtin_amdgcn_mfma_f32_16x16x32_f16(w1f[1][nt].h, a1.h, acc, 0, 0, 0);
                uint2 hv;
                hv.x = pk2(fmaxf(acc[0], 0.0f), fmaxf(acc[1], 0.0f));
                hv.y = pk2(fmaxf(acc[2], 0.0f), fmaxf(acc[3], 0.0f));
                *(uint2*)(wbase + nt * (2 * HBS)) = hv;
            }
        }
        __syncthreads();           // h ready; sem free

        // conv2 (swapped): 9 tap-GEMMs; TWO independent accumulator chains
        // (ks=0 -> cacc0 with bias, ks=1 -> cacc1 zero-seeded), summed at end.
        #pragma unroll
        for (int i = 0; i < 4; ++i) {
            const int mt = wv * 4 + i;
            const int pp = (mt + 1) * PW + (ln + 1);
            const char* hb0 = s_hb + g * HBS + pp * 16;        // ks=0 block
            const char* hb1 = hb0 + 4 * HBS;                   // ks=1 block
            f32x4 cacc0, cacc1;
            cacc0[0] = (g == 0) ? b2v.x : 0.0f;
            cacc0[1] = (g == 0) ? b2v.y : 0.0f;
            cacc0[2] = (g == 0) ? b2v.z : 0.0f;
            cacc0[3] = (g == 0) ? b2v.w : 0.0f;
            cacc1[0] = 0.0f; cacc1[1] = 0.0f; cacc1[2] = 0.0f; cacc1[3] = 0.0f;
            #pragma unroll
            for (int tp = 0; tp < 9; ++tp) {
                F8U af0, af1;
                af0.u = *(const uint4*)(hb0 + OFF[tp] * 16);
                af1.u = *(const uint4*)(hb1 + OFF[tp] * 16);
                cacc0 = __builtin_amdgcn_mfma_f32_16x16x32_f16(w2f[tp][0].h, af0.h, cacc0, 0, 0, 0);
                cacc1 = __builtin_amdgcn_mfma_f32_16x16x32_f16(w2f[tp][1].h, af1.h, cacc1, 0, 0, 0);
            }
            if (g == 0) {
                float x0 = cacc0[0] + cacc1[0];
                float x1 = cacc0[1] + cacc1[1];
                float x2 = cacc0[2] + cacc1[2];
                float x3 = cacc0[3] + cacc1[3];
                float c0s = fmaxf(x0, 0.0f) + __logf(1.0f + __expf(-fabsf(x0))) + 1e-6f;
                float c1s = fmaxf(x1, 0.0f) + __logf(1.0f + __expf(-fabsf(x1))) + 1e-6f;
                float c2s = fmaxf(x2, 0.0f) + __logf(1.0f + __expf(-fabsf(x2))) + 1e-6f;
                float c3s = fmaxf(x3, 0.0f) + __logf(1.0f + __expf(-fabsf(x3))) + 1e-6f;
                s_costh[e][mt * 16 + ln] = make_uint2(pk2(c0s, c1s), pk2(c2s, c3s));
            }
        }
        // softmax for next element (sem readers done at conv1's barrier)
        if (e < 3) {
            float x0 = gi[e+1][0] * th[0], x1 = gi[e+1][1] * th[1];
            float x2 = gi[e+1][2] * th[2], x3 = gi[e+1][3] * th[3];
            float m  = fmaxf(fmaxf(x0, x1), fmaxf(x2, x3));
            float e0 = __expf(x0 - m), e1 = __expf(x1 - m);
            float e2 = __expf(x2 - m), e3 = __expf(x3 - m);
            float inv = 1.0f / (e0 + e1 + e2 + e3);
            s_sem[(pr + 1) * PW + (pc + 1)] =
                make_uint2(pk2(e0 * inv, e1 * inv), pk2(e2 * inv, e3 * inv));
        }
        __syncthreads();           // h free for next conv1; cost[e] committed
    }

    // ---- value iteration: wave wv owns element b0+wv (Jacobi, 2 inner/outer) ----
    {
        const int cv  = ln;
        const int rgv = g;
        const int r0  = rgv * 4;

        float cs[4][4];
        #pragma unroll
        for (int i = 0; i < 4; ++i) {
            const uint2 cw = s_costh[wv][(r0 + i) * GSZ + cv];
            UH2 a, bq; a.u = cw.x; bq.u = cw.y;
            cs[i][0] = (float)a.h[0];  cs[i][1] = (float)a.h[1];
            cs[i][2] = (float)bq.h[0]; cs[i][3] = (float)bq.h[1];
        }

        float gg[4];
        #pragma unroll
        for (int i = 0; i < 4; ++i)
            gg[i] = (cv == gcc && (r0 + i) == grr) ? 0.0f : LBIG;

        for (int k = 0; k < 128; ++k) {
            const float gu = __shfl_up(gg[3], 16);
            const float gd = __shfl_down(gg[0], 16);
            const float up0 = (rgv > 0) ? gu : LBIG;
            const float dn3 = (rgv < 3) ? gd : LBIG;
            bool ch = false;
            #pragma unroll
            for (int s = 0; s < 2; ++s) {
                float lf[4], rt[4];
                #pragma unroll
                for (int i = 0; i < 4; ++i) { lf[i] = dpp_up1(gg[i]); rt[i] = dpp_dn1(gg[i]); }
                #pragma unroll
                for (int i = 0; i < 4; ++i) {
                    lf[i] = (cv > 0)  ? lf[i] : LBIG;
                    rt[i] = (cv < 15) ? rt[i] : LBIG;
                }
                const float up[4] = { up0, gg[0], gg[1], gg[2] };
                const float dn[4] = { gg[1], gg[2], gg[3], dn3 };
                #pragma unroll
                for (int i = 0; i < 4; ++i) {
                    float q = fminf(fminf(cs[i][0] + up[i], cs[i][1] + dn[i]),
                                    fminf(cs[i][2] + lf[i], cs[i][3] + rt[i]));
                    float ng = fminf(gg[i], q);
                    ch = ch || (ng < gg[i]);
                    gg[i] = ng;
                }
            }
            if (__ballot(ch) == 0ULL) break;   // per-wave fixed point
        }

        #pragma unroll
        for (int i = 0; i < 4; ++i)
            s_gout[wv * NPIX + (r0 + i) * GSZ + cv] = gg[i];
    }
    // intra-wave LDS ordering only (same wave writes then reads; no barrier)

    // ---- Q gather + output softmax: lane 0 of each wave ----
    if (lane == 0) {
        const int lp = lr * GSZ + lc;
        const uint2 cw = s_costh[wv][lp];
        UH2 a, bq; a.u = cw.x; bq.u = cw.y;
        float Q0 = (float)a.h[0]  + s_gout[wv * NPIX + lp - GSZ];
        float Q1 = (float)a.h[1]  + s_gout[wv * NPIX + lp + GSZ];
        float Q2 = (float)bq.h[0] + s_gout[wv * NPIX + lp - 1];
        float Q3 = (float)bq.h[1] + s_gout[wv * NPIX + lp + 1];
        float l0 = -Q0, l1 = -Q1, l2 = -Q2, l3 = -Q3;
        float m  = fmaxf(fmaxf(l0, l1), fmaxf(l2, l3));
        float e0 = __expf(l0 - m), e1 = __expf(l1 - m);
        float e2 = __expf(l2 - m), e3 = __expf(l3 - m);
        float inv = 1.0f / (e0 + e1 + e2 + e3);
        float* lo = out + (size_t)eidx * 4;
        float* po = out + (size_t)B * 4 + (size_t)eidx * 4;
        lo[0] = l0; lo[1] = l1; lo[2] = l2; lo[3] = l3;
        po[0] = e0 * inv; po[1] = e1 * inv; po[2] = e2 * inv; po[3] = e3 * inv;
    }
}

extern "C" void kernel_launch(void* const* d_in, const int* in_sizes, int n_in,
                              void* d_out, int out_size, void* d_ws, size_t ws_size,
                              hipStream_t stream) {
    const float* grid_cnt = (const float*)d_in[0];
    const int*   loc      = (const int*)  d_in[1];
    const int*   goal     = (const int*)  d_in[2];
    const float* theta    = (const float*)d_in[3];
    const float* w1       = (const float*)d_in[4];
    const float* b1       = (const float*)d_in[5];
    const float* w2       = (const float*)d_in[6];
    const float* b2       = (const float*)d_in[7];
    float*       outp     = (float*)d_out;
    __fp16*      pw       = (__fp16*)d_ws;     // needs 26624 B
    const int B = in_sizes[1] / 2;   // loc_batch is (B,2)

    hipLaunchKernelGGL(pack_weights, dim3(52), dim3(256), 0, stream, w1, w2, pw);
    hipLaunchKernelGGL(semirl_kernel, dim3(B / 4), dim3(256), 0, stream,
                       grid_cnt, loc, goal, theta, b1, b2, pw, outp, B);
}

// Round 16
// 31.889 us; speedup vs baseline: 1.2614x; 1.0657x over previous
//
#include <hip/hip_runtime.h>
#include <math.h>

#define GSZ   16
#define NPIX  256
#define LBIG  1.0e6f
#define PW    18
#define PP18  324
#define HBS   (PP18 * 16)       // bytes per oc-block in h tile

typedef __fp16 f16x8 __attribute__((ext_vector_type(8)));
typedef __fp16 h2v   __attribute__((ext_vector_type(2)));
typedef float  f32x4 __attribute__((ext_vector_type(4)));
union UH2 { unsigned u; h2v h; };
union F8U { f16x8 h; uint4 u; unsigned w[4]; };
union UF  { unsigned u; float f; };

__device__ __forceinline__ unsigned pk2(float a, float b) {
    UH2 u; u.h = __builtin_amdgcn_cvt_pkrtz(a, b);
    return u.u;
}
// packed relu: v_pk_max_f16(cvt_pkrtz(a,b), 0)
__device__ __forceinline__ unsigned pk2relu(float a, float b) {
    UH2 u; u.h = __builtin_amdgcn_cvt_pkrtz(a, b);
    h2v z = { (__fp16)0.0f, (__fp16)0.0f };
    u.h = __builtin_elementwise_max(u.h, z);
    return u.u;
}
// value from lane-1 within each 16-lane row: DPP row_shr:1 (0 at row lane 0)
__device__ __forceinline__ float dpp_up1(float x) {
    UF s; s.f = x; UF r;
    r.u = (unsigned)__builtin_amdgcn_update_dpp(0, (int)s.u, 0x111, 0xF, 0xF, true);
    return r.f;
}
// value from lane+1 within each 16-lane row: DPP row_shl:1 (0 at row lane 15)
__device__ __forceinline__ float dpp_dn1(float x) {
    UF s; s.f = x; UF r;
    r.u = (unsigned)__builtin_amdgcn_update_dpp(0, (int)s.u, 0x101, 0xF, 0xF, true);
    return r.f;
}

// ---- prep: pack weights into MFMA fragment order ----
__global__ void pack_weights(const float* __restrict__ w1,
                             const float* __restrict__ w2,
                             __fp16* __restrict__ pw) {
    int i = blockIdx.x * 256 + threadIdx.x;
    if (i < 4096) {
        int j = i & 7, lane = (i >> 3) & 63, t = i >> 9;   // t = ks*4+nt
        int ks = t >> 2, nt = t & 3;
        int oc = nt * 16 + (lane & 15);
        int k  = ks * 32 + ((lane >> 4) & 3) * 8 + j;
        int tap = k >> 2, cls = k & 3;
        pw[i] = (tap < 9) ? (__fp16)w1[oc * 36 + cls * 9 + tap] : (__fp16)0.0f;
    } else if (i < 4096 + 9216) {
        int m = i - 4096;
        int j = m & 7, lane = (m >> 3) & 63, t = m >> 9;   // t = tap*2+ks
        int ks = t & 1, tap = t >> 1;
        int u  = lane & 15;
        int oc = ks * 32 + ((lane >> 4) & 3) * 8 + j;
        pw[i] = (u < 4) ? (__fp16)w2[u * 576 + oc * 9 + tap] : (__fp16)0.0f;
    }
}

// ring index for border pixel t in [0,68) of the 18x18 ring
__device__ __forceinline__ int ring_idx(int t) {
    return (t < 18) ? t
         : (t < 36) ? (306 + (t - 18))
         : (t < 52) ? ((t - 35) * PW)
                    : ((t - 51) * PW + 17);
}

__global__ __launch_bounds__(256, 2) void semirl_kernel(
    const float*  __restrict__ grid_cnt,  // (B,4,16,16)
    const int*    __restrict__ loc,       // (B,2)
    const int*    __restrict__ goal,      // (B,2)
    const float*  __restrict__ theta,     // (4,16,16)
    const float*  __restrict__ b1,        // (64)
    const float*  __restrict__ b2,        // (4)
    const __fp16* __restrict__ pw,        // packed weight fragments (d_ws)
    float*        __restrict__ out,       // logits (B,4) then probs (B,4)
    int B)
{
    const int b0   = blockIdx.x * 4;      // 4 batch elements per block
    const int tid  = threadIdx.x;
    const int lane = tid & 63;
    const int wv   = tid >> 6;            // wave id 0..3 = element owner for VI
    const int g    = (lane >> 4) & 3;     // k-group / row-group
    const int ln   = lane & 15;

    __shared__ uint2 s_sem[PP18];             // fp16x2 class pairs, zero ring (2.6K)
    __shared__ uint4 s_h4[8 * PP18];          // h: [ocblk][ringpix] 16B (41.5K)
    __shared__ uint2 s_costh[4][NPIX];        // cost fp16 pairs [elem][pix] (8K)
    char*  s_hb   = (char*)s_h4;
    float* s_gout = (float*)s_h4;             // [4][NPIX] aliased (h dead post-conv)

    // ---- prefetch all globals (latency hides under phase 0) ----
    F8U w1f[2][4];
    {
        const uint4* p1 = (const uint4*)pw;
        #pragma unroll
        for (int ks = 0; ks < 2; ++ks)
            #pragma unroll
            for (int nt = 0; nt < 4; ++nt)
                w1f[ks][nt].u = p1[(ks * 4 + nt) * 64 + lane];
    }
    F8U w2f[9][2];
    {
        const uint4* p2 = (const uint4*)(pw + 4096);
        #pragma unroll
        for (int tp = 0; tp < 9; ++tp)
            #pragma unroll
            for (int ks = 0; ks < 2; ++ks)
                w2f[tp][ks].u = p2[(tp * 2 + ks) * 64 + lane];
    }
    float4 bias1v[4];
    #pragma unroll
    for (int nt = 0; nt < 4; ++nt)
        bias1v[nt] = *(const float4*)&b1[nt * 16 + g * 4];
    const float4 b2v = *(const float4*)b2;

    const int eidx = b0 + wv;              // this wave's VI element
    const int grr = goal[2 * eidx], gcc = goal[2 * eidx + 1];
    const int lr  = loc[2 * eidx],  lc  = loc[2 * eidx + 1];

    float th[4], gi[4][4];
    #pragma unroll
    for (int c = 0; c < 4; ++c) th[c] = theta[c * NPIX + tid];
    #pragma unroll
    for (int e = 0; e < 4; ++e)
        #pragma unroll
        for (int c = 0; c < 4; ++c)
            gi[e][c] = grid_cnt[(size_t)(b0 + e) * (4 * NPIX) + c * NPIX + tid];

    // ---- phase 0: ring zeros (once) + softmax elem 0 ----
    if (tid < 68) s_sem[ring_idx(tid)] = make_uint2(0u, 0u);
    for (int i2 = tid; i2 < 544; i2 += 256) {
        int qq = ring_idx(i2 >> 3);
        s_h4[(i2 & 7) * PP18 + qq] = make_uint4(0u, 0u, 0u, 0u);
    }
    const int pr = tid >> 4, pc = tid & 15;
    {
        float x0 = gi[0][0] * th[0], x1 = gi[0][1] * th[1];
        float x2 = gi[0][2] * th[2], x3 = gi[0][3] * th[3];
        float m  = fmaxf(fmaxf(x0, x1), fmaxf(x2, x3));
        float e0 = __expf(x0 - m), e1 = __expf(x1 - m);
        float e2 = __expf(x2 - m), e3 = __expf(x3 - m);
        float inv = 1.0f / (e0 + e1 + e2 + e3);
        s_sem[(pr + 1) * PW + (pc + 1)] =
            make_uint2(pk2(e0 * inv, e1 * inv), pk2(e2 * inv, e3 * inv));
    }
    __syncthreads();

    const int off0 = (g == 0) ? (-PW - 1) : (g == 1) ? (-PW + 1) : (g == 2) ? 0 : (PW - 1);
    const int off1 = (g == 0) ? (-PW)     : (g == 1) ? (-1)      : (g == 2) ? 1 : PW;
    const int OFF[9] = { -PW - 1, -PW, -PW + 1, -1, 0, 1, PW - 1, PW, PW + 1 };

    // ---- element-sequential convs: all 4 waves cooperate per element ----
    #pragma unroll
    for (int e = 0; e < 4; ++e) {
        // conv1 (swapped: D' = W^T x Act^T), write h fragments
        #pragma unroll
        for (int i = 0; i < 4; ++i) {
            const int mt = wv * 4 + i;
            const int pp = (mt + 1) * PW + (ln + 1);
            const uint2 A0 = s_sem[pp + off0];
            const uint2 A1 = s_sem[pp + off1];
            const uint2 A2 = s_sem[pp + (PW + 1)];   // tap8; dead slots zero-weighted
            F8U a0, a1;
            a0.w[0] = A0.x; a0.w[1] = A0.y; a0.w[2] = A1.x; a0.w[3] = A1.y;
            a1.w[0] = A2.x; a1.w[1] = A2.y; a1.w[2] = 0u;  a1.w[3] = 0u;
            char* wbase = s_hb + (g >> 1) * HBS + pp * 16 + (g & 1) * 8;
            #pragma unroll
            for (int nt = 0; nt < 4; ++nt) {
                f32x4 acc = { bias1v[nt].x, bias1v[nt].y, bias1v[nt].z, bias1v[nt].w };
                acc = __builtin_amdgcn_mfma_f32_16x16x32_f16(w1f[0][nt].h, a0.h, acc, 0, 0, 0);
                acc = __builtin_amdgcn_mfma_f32_16x16x32_f16(w1f[1][nt].h, a1.h, acc, 0, 0, 0);
                uint2 hv;
                hv.x = pk2relu(acc[0], acc[1]);
                hv.y = pk2relu(acc[2], acc[3]);
                *(uint2*)(wbase + nt * (2 * HBS)) = hv;
            }
        }
        __syncthreads();           // h ready; sem free

        // conv2 (swapped): 9 tap-GEMMs; TWO independent accumulator chains
        #pragma unroll
        for (int i = 0; i < 4; ++i) {
            const int mt = wv * 4 + i;
            const int pp = (mt + 1) * PW + (ln + 1);
            const char* hb0 = s_hb + g * HBS + pp * 16;        // ks=0 block
            const char* hb1 = hb0 + 4 * HBS;                   // ks=1 block
            f32x4 cacc0, cacc1;
            cacc0[0] = (g == 0) ? b2v.x : 0.0f;
            cacc0[1] = (g == 0) ? b2v.y : 0.0f;
            cacc0[2] = (g == 0) ? b2v.z : 0.0f;
            cacc0[3] = (g == 0) ? b2v.w : 0.0f;
            cacc1[0] = 0.0f; cacc1[1] = 0.0f; cacc1[2] = 0.0f; cacc1[3] = 0.0f;
            #pragma unroll
            for (int tp = 0; tp < 9; ++tp) {
                F8U af0, af1;
                af0.u = *(const uint4*)(hb0 + OFF[tp] * 16);
                af1.u = *(const uint4*)(hb1 + OFF[tp] * 16);
                cacc0 = __builtin_amdgcn_mfma_f32_16x16x32_f16(w2f[tp][0].h, af0.h, cacc0, 0, 0, 0);
                cacc1 = __builtin_amdgcn_mfma_f32_16x16x32_f16(w2f[tp][1].h, af1.h, cacc1, 0, 0, 0);
            }
            if (g == 0) {
                float x0 = cacc0[0] + cacc1[0];
                float x1 = cacc0[1] + cacc1[1];
                float x2 = cacc0[2] + cacc1[2];
                float x3 = cacc0[3] + cacc1[3];
                float c0s = fmaxf(x0, 0.0f) + __logf(1.0f + __expf(-fabsf(x0))) + 1e-6f;
                float c1s = fmaxf(x1, 0.0f) + __logf(1.0f + __expf(-fabsf(x1))) + 1e-6f;
                float c2s = fmaxf(x2, 0.0f) + __logf(1.0f + __expf(-fabsf(x2))) + 1e-6f;
                float c3s = fmaxf(x3, 0.0f) + __logf(1.0f + __expf(-fabsf(x3))) + 1e-6f;
                s_costh[e][mt * 16 + ln] = make_uint2(pk2(c0s, c1s), pk2(c2s, c3s));
            }
        }
        // softmax for next element (sem readers done at conv1's barrier)
        if (e < 3) {
            float x0 = gi[e+1][0] * th[0], x1 = gi[e+1][1] * th[1];
            float x2 = gi[e+1][2] * th[2], x3 = gi[e+1][3] * th[3];
            float m  = fmaxf(fmaxf(x0, x1), fmaxf(x2, x3));
            float e0 = __expf(x0 - m), e1 = __expf(x1 - m);
            float e2 = __expf(x2 - m), e3 = __expf(x3 - m);
            float inv = 1.0f / (e0 + e1 + e2 + e3);
            s_sem[(pr + 1) * PW + (pc + 1)] =
                make_uint2(pk2(e0 * inv, e1 * inv), pk2(e2 * inv, e3 * inv));
        }
        __syncthreads();           // h free for next conv1; cost[e] committed
    }

    // ---- value iteration: wave wv owns element b0+wv (Jacobi, 2 inner/outer) ----
    // Boundary handling baked into cs: out-of-grid direction costs = LBIG, so
    // boundary candidates (LBIG + {0 or stale value}) are never selected --
    // exact same min results as explicit cndmask clamps, with zero per-iter cost.
    {
        const int cv  = ln;
        const int rgv = g;
        const int r0  = rgv * 4;

        float cs[4][4];
        #pragma unroll
        for (int i = 0; i < 4; ++i) {
            const uint2 cw = s_costh[wv][(r0 + i) * GSZ + cv];
            UH2 a, bq; a.u = cw.x; bq.u = cw.y;
            cs[i][0] = (float)a.h[0];  cs[i][1] = (float)a.h[1];
            cs[i][2] = (float)bq.h[0]; cs[i][3] = (float)bq.h[1];
        }
        if (cv == 0)  { cs[0][2] = LBIG; cs[1][2] = LBIG; cs[2][2] = LBIG; cs[3][2] = LBIG; }
        if (cv == 15) { cs[0][3] = LBIG; cs[1][3] = LBIG; cs[2][3] = LBIG; cs[3][3] = LBIG; }
        if (rgv == 0) cs[0][0] = LBIG;
        if (rgv == 3) cs[3][1] = LBIG;

        float gg[4];
        #pragma unroll
        for (int i = 0; i < 4; ++i)
            gg[i] = (cv == gcc && (r0 + i) == grr) ? 0.0f : LBIG;

        for (int k = 0; k < 128; ++k) {
            const float gu = __shfl_up(gg[3], 16);    // self at rgv==0: masked by cs
            const float gd = __shfl_down(gg[0], 16);  // self at rgv==3: masked by cs
            bool ch = false;
            #pragma unroll
            for (int s = 0; s < 2; ++s) {
                float lf[4], rt[4];
                #pragma unroll
                for (int i = 0; i < 4; ++i) { lf[i] = dpp_up1(gg[i]); rt[i] = dpp_dn1(gg[i]); }
                const float up[4] = { gu, gg[0], gg[1], gg[2] };
                const float dn[4] = { gg[1], gg[2], gg[3], gd };
                #pragma unroll
                for (int i = 0; i < 4; ++i) {
                    float s0 = cs[i][0] + up[i];
                    float s1 = cs[i][1] + dn[i];
                    float s2 = cs[i][2] + lf[i];
                    float s3 = cs[i][3] + rt[i];
                    // min3-friendly: min of 5 in two v_min3
                    float q  = fminf(fminf(fminf(s0, s1), s2), fminf(s3, gg[i]));
                    ch = ch || (q < gg[i]);
                    gg[i] = q;
                }
            }
            if (__ballot(ch) == 0ULL) break;   // per-wave fixed point
        }

        #pragma unroll
        for (int i = 0; i < 4; ++i)
            s_gout[wv * NPIX + (r0 + i) * GSZ + cv] = gg[i];
    }
    // intra-wave LDS ordering only (same wave writes then reads; no barrier)

    // ---- Q gather + output softmax: lane 0 of each wave ----
    if (lane == 0) {
        const int lp = lr * GSZ + lc;
        const uint2 cw = s_costh[wv][lp];
        UH2 a, bq; a.u = cw.x; bq.u = cw.y;
        float Q0 = (float)a.h[0]  + s_gout[wv * NPIX + lp - GSZ];
        float Q1 = (float)a.h[1]  + s_gout[wv * NPIX + lp + GSZ];
        float Q2 = (float)bq.h[0] + s_gout[wv * NPIX + lp - 1];
        float Q3 = (float)bq.h[1] + s_gout[wv * NPIX + lp + 1];
        float l0 = -Q0, l1 = -Q1, l2 = -Q2, l3 = -Q3;
        float m  = fmaxf(fmaxf(l0, l1), fmaxf(l2, l3));
        float e0 = __expf(l0 - m), e1 = __expf(l1 - m);
        float e2 = __expf(l2 - m), e3 = __expf(l3 - m);
        float inv = 1.0f / (e0 + e1 + e2 + e3);
        float* lo = out + (size_t)eidx * 4;
        float* po = out + (size_t)B * 4 + (size_t)eidx * 4;
        lo[0] = l0; lo[1] = l1; lo[2] = l2; lo[3] = l3;
        po[0] = e0 * inv; po[1] = e1 * inv; po[2] = e2 * inv; po[3] = e3 * inv;
    }
}

extern "C" void kernel_launch(void* const* d_in, const int* in_sizes, int n_in,
                              void* d_out, int out_size, void* d_ws, size_t ws_size,
                              hipStream_t stream) {
    const float* grid_cnt = (const float*)d_in[0];
    const int*   loc      = (const int*)  d_in[1];
    const int*   goal     = (const int*)  d_in[2];
    const float* theta    = (const float*)d_in[3];
    const float* w1       = (const float*)d_in[4];
    const float* b1       = (const float*)d_in[5];
    const float* w2       = (const float*)d_in[6];
    const float* b2       = (const float*)d_in[7];
    float*       outp     = (float*)d_out;
    __fp16*      pw       = (__fp16*)d_ws;     // needs 26624 B
    const int B = in_sizes[1] / 2;   // loc_batch is (B,2)

    hipLaunchKernelGGL(pack_weights, dim3(52), dim3(256), 0, stream, w1, w2, pw);
    hipLaunchKernelGGL(semirl_kernel, dim3(B / 4), dim3(256), 0, stream,
                       grid_cnt, loc, goal, theta, b1, b2, pw, outp, B);
}